// Round 13
// baseline (318.420 us; speedup 1.0000x reference)
//
#include <hip/hip_runtime.h>

#define NNODES 102400

__device__ __forceinline__ float ftanh(float x) {
    float a = fabsf(x);
    float e = __expf(-2.0f * a);
    float t = (1.0f - e) / (1.0f + e);
    return copysignf(t, x);
}

// ---------------- FC1 ----------------
__global__ __launch_bounds__(256) void fc1_kernel(
    const float* __restrict__ x, const float* __restrict__ w1,
    const float* __restrict__ b1, float* __restrict__ h1t)
{
    const int b = threadIdx.x & 63;
    const int o = blockIdx.x * 4 + __builtin_amdgcn_readfirstlane(threadIdx.x >> 6);
    const float* xr = x + b * 128;
    const float* wr = w1 + o * 128;
    float acc = 0.f;
#pragma unroll
    for (int k = 0; k < 128; ++k) acc = fmaf(xr[k], wr[k], acc);
    h1t[o * 64 + b] = ftanh(acc + b1[o]);
}

// ---------------- FC2 as LDS-tiled GEMM ----------------
__global__ __launch_bounds__(128) void fc2_gemm_kernel(
    const float* __restrict__ h1t,   // [1024][64]
    const float* __restrict__ w2,    // [12832][1024]
    float* __restrict__ part)        // [4][12832][64]
{
    __shared__ float Wl[32][68];
    __shared__ float Hl[64][64];
    const int t  = threadIdx.x;
    const int o0 = blockIdx.x * 32;
    const int ks = blockIdx.y;
    const int ob = (t >> 4) * 4;
    const int b4 = (t & 15) * 4;

    float acc[4][4] = {};
    const int kbase = ks * 256;
#pragma unroll 1
    for (int kt = 0; kt < 4; ++kt) {
        const int k0 = kbase + kt * 64;
        {
            const int row = t >> 2;
            const int c0  = (t & 3) * 4;
            const float* src = w2 + (size_t)(o0 + row) * 1024 + k0;
#pragma unroll
            for (int i = 0; i < 4; ++i) {
                const float4 v = *reinterpret_cast<const float4*>(src + c0 + 16 * i);
                *reinterpret_cast<float4*>(&Wl[row][c0 + 16 * i]) = v;
            }
        }
        {
            const float* src = h1t + (size_t)k0 * 64;
            float* dst = &Hl[0][0];
#pragma unroll
            for (int i = 0; i < 8; ++i) {
                const int f4 = t + 128 * i;
                const float4 v = *reinterpret_cast<const float4*>(src + f4 * 4);
                *reinterpret_cast<float4*>(dst + f4 * 4) = v;
            }
        }
        __syncthreads();
#pragma unroll
        for (int kk = 0; kk < 16; ++kk) {
            const int k4 = kk * 4;
            float wv[4][4], hv[4][4];
#pragma unroll
            for (int i = 0; i < 4; ++i) {
                const float4 v = *reinterpret_cast<const float4*>(&Wl[ob + i][k4]);
                wv[i][0] = v.x; wv[i][1] = v.y; wv[i][2] = v.z; wv[i][3] = v.w;
            }
#pragma unroll
            for (int j = 0; j < 4; ++j) {
                const float4 v = *reinterpret_cast<const float4*>(&Hl[k4 + j][b4]);
                hv[j][0] = v.x; hv[j][1] = v.y; hv[j][2] = v.z; hv[j][3] = v.w;
            }
#pragma unroll
            for (int i = 0; i < 4; ++i)
#pragma unroll
                for (int j = 0; j < 4; ++j)
#pragma unroll
                    for (int jb = 0; jb < 4; ++jb)
                        acc[i][jb] = fmaf(wv[i][j], hv[j][jb], acc[i][jb]);
        }
        __syncthreads();
    }
    float* pb = part + ((size_t)ks * 12832 + o0) * 64;
#pragma unroll
    for (int i = 0; i < 4; ++i) {
        const float4 v = make_float4(acc[i][0], acc[i][1], acc[i][2], acc[i][3]);
        *reinterpret_cast<float4*>(pb + (size_t)(ob + i) * 64 + b4) = v;
    }
}

__global__ __launch_bounds__(256) void fc2_reduce_kernel(
    const float* __restrict__ part, const float* __restrict__ b2,
    float* __restrict__ h2t)
{
    const int idx = blockIdx.x * 256 + threadIdx.x;
    const int o = idx >> 6;
    const float s = part[idx] + part[821248 + idx]
                  + part[1642496 + idx] + part[2463744 + idx];
    h2t[idx] = ftanh(s + b2[o]);
}

// ---------------- weight pre-pack: w[i][ci][co][k] -> wp[i][k0][d][ci][co] ----------------
__device__ __forceinline__ void pack_one(const float* __restrict__ w, float* __restrict__ wp,
                                         int CIN, int COUT, int idx)
{
    const int k = idx & 31;
    int r = idx >> 5;
    const int co = r % COUT; r /= COUT;
    const int ci = r % CIN;
    const int i  = r / CIN;
    const int k0 = k & 3, d = k >> 2;
    wp[(((i * 4 + k0) * 8 + d) * CIN + ci) * COUT + co] = w[idx];
}

__global__ __launch_bounds__(256) void pack_all_kernel(
    const float* __restrict__ w1, const float* __restrict__ w2,
    const float* __restrict__ w3, const float* __restrict__ w4,
    float* __restrict__ wp1, float* __restrict__ wp2,
    float* __restrict__ wp3, float* __restrict__ wp4)
{
    const int idx = blockIdx.x * 256 + threadIdx.x;
    if (idx < 16384)       pack_one(w1, wp1, 16, 16, idx);
    else if (idx < 32768)  pack_one(w2, wp2, 16, 16, idx - 16384);
    else if (idx < 40960)  pack_one(w3, wp3, 16,  8, idx - 32768);
    else if (idx < 41472)  pack_one(w4, wp4,  8,  1, idx - 40960);
}

// ---------------- ConvTranspose1d core (r9 known-good: rolled ci, imm-offset) ------
template<int CIN, int CPG, int TT, int JSTR, bool GUARD>
__device__ __forceinline__ void conv_core(
    const float* __restrict__ xs, int cistride, int Lin,
    const float* __restrict__ wk, int wco, int jhi0, float (&acc)[TT][CPG])
{
    constexpr int NJ = TT + 7;
    const int jlo = jhi0 - 7;
    const float* xsj = xs + (ptrdiff_t)jlo * JSTR;
    for (int ci = 0; ci < CIN; ++ci) {               // rolled
        float xv[NJ];
        if constexpr (GUARD) {
            const float* xpc = xs + (size_t)ci * cistride;
#pragma unroll
            for (int q = 0; q < NJ; ++q) {
                const int j = jlo + q;
                xv[q] = (j >= 0 && j < Lin) ? xpc[(ptrdiff_t)j * JSTR] : 0.f;
            }
        } else {
            const float* xpc = xsj + (size_t)ci * cistride;
#pragma unroll
            for (int q = 0; q < NJ; ++q)
                xv[q] = xpc[q * JSTR];               // imm-offset loads
        }
        const float* wc = wk + ci * wco;
#pragma unroll
        for (int d = 0; d < 8; ++d) {
            const float* wd = wc + d * CIN * wco;
            float wv[CPG];
            if constexpr ((CPG & 3) == 0) {
#pragma unroll
                for (int cq = 0; cq < CPG; cq += 4) {
                    const float4 w4 = *reinterpret_cast<const float4*>(wd + cq);
                    wv[cq + 0] = w4.x; wv[cq + 1] = w4.y;
                    wv[cq + 2] = w4.z; wv[cq + 3] = w4.w;
                }
            } else {
#pragma unroll
                for (int co = 0; co < CPG; ++co) wv[co] = wd[co];
            }
#pragma unroll
            for (int tt = 0; tt < TT; ++tt) {
                const float xx = xv[7 + tt - d];
#pragma unroll
                for (int co = 0; co < CPG; ++co)
                    acc[tt][co] = fmaf(xx, wv[co], acc[tt][co]);
            }
        }
    }
}

template<int CIN, int COUT, int TT, int COG, int MINW, int JSTR>
__global__ __launch_bounds__(256, MINW) void convt3_kernel(
    const float* __restrict__ x, size_t sfc_xstride, int cistride,
    const float* __restrict__ wp, int sfc_wstride,
    const float* __restrict__ bias, int sfc_bstride,
    float* __restrict__ y, size_t sfc_ystride,
    int Lin, int Lout)
{
    constexpr int CPG = COUT / COG;
    const int b = threadIdx.x & 63;
    const int widx = __builtin_amdgcn_readfirstlane(threadIdx.x >> 6);
    const int t0 = blockIdx.x * (4 * TT) + widx;
    if (t0 >= Lout) return;
    const int cb = blockIdx.z * CPG;
    const int k0   = (t0 + 16) & 3;
    const int jhi0 = (t0 + 16) >> 2;
    const float* xs = x + (size_t)blockIdx.y * sfc_xstride + b;
    const float* wk = wp + blockIdx.y * sfc_wstride + k0 * (8 * CIN * COUT) + cb;
    const float* bs = bias + blockIdx.y * sfc_bstride + cb;

    float acc[TT][CPG];
#pragma unroll
    for (int co = 0; co < CPG; ++co) {
        const float bv = bs[co];
#pragma unroll
        for (int tt = 0; tt < TT; ++tt) acc[tt][co] = bv;
    }

    const bool interior = (jhi0 >= 7) && (jhi0 + TT - 1 < Lin);
    if (interior)
        conv_core<CIN, CPG, TT, JSTR, false>(xs, cistride, Lin, wk, COUT, jhi0, acc);
    else
        conv_core<CIN, CPG, TT, JSTR, true >(xs, cistride, Lin, wk, COUT, jhi0, acc);

#pragma unroll
    for (int tt = 0; tt < TT; ++tt) {
        const int t = t0 + 4 * tt;
        if (t < Lout) {
#pragma unroll
            for (int co = 0; co < CPG; ++co)
                y[(size_t)blockIdx.y * sfc_ystride + ((size_t)(cb + co) * Lout + t) * 64 + b] =
                    ftanh(acc[tt][co]);
        }
    }
}

// ---------------- conv3 LDS-staged: 512 thr, 32 outputs/block, whole window in LDS ----
// Wave w: k0=w&3, h=w>>2; t = T0 + 16h + k0 + 4tt. Window rows J0-7 .. J0+7 (15).
// Compute reads Xl[ci][4h+q][b]: bank = b%32 -> 2-way (free). One barrier total.
__global__ __launch_bounds__(512, 4) void convt3_lds_kernel(
    const float* __restrict__ x, size_t sfc_xstride,   // x[ci][j][64], per-sfc stride
    const float* __restrict__ wp, int sfc_wstride,     // wp[k0][d][ci][co], co=8
    const float* __restrict__ bias, int sfc_bstride,
    float* __restrict__ y, size_t sfc_ystride,
    int Lin, int Lout)                                 // 6401, 25601
{
    constexpr int CIN = 16, CO = 8, TT = 4, NROW = 15;
    __shared__ float Xl[CIN][NROW][64];                // 60 KB
    const int tid = threadIdx.x;
    const int T0 = blockIdx.x * 32;
    const int J0 = (T0 + 16) >> 2;
    const int jbase = J0 - 7;
    const float* xb = x + (size_t)blockIdx.y * sfc_xstride;

    // stage 15360 floats = 3840 float4 via 512 threads (8 iters, guarded)
#pragma unroll
    for (int it = 0; it < 8; ++it) {
        const int f = tid + it * 512;
        if (f < CIN * NROW * 16) {
            const int c4  = f & 15;
            const int row = (f >> 4) % NROW;
            const int ci  = (f >> 4) / NROW;
            const int j = jbase + row;
            float4 v = make_float4(0.f, 0.f, 0.f, 0.f);
            if (j >= 0 && j < Lin)
                v = *reinterpret_cast<const float4*>(xb + ((size_t)ci * Lin + j) * 64 + c4 * 4);
            *reinterpret_cast<float4*>(&Xl[ci][row][c4 * 4]) = v;
        }
    }
    __syncthreads();

    const int b = tid & 63;
    const int w = __builtin_amdgcn_readfirstlane(tid >> 6);   // 0..7
    const int k0 = w & 3;
    const int h  = w >> 2;
    const int t0 = T0 + 16 * h + k0;
    const float* wk = wp + blockIdx.y * sfc_wstride + k0 * (8 * CIN * CO);
    const float* bs = bias + blockIdx.y * sfc_bstride;

    float acc[TT][CO];
#pragma unroll
    for (int co = 0; co < CO; ++co) {
        const float bv = bs[co];
#pragma unroll
        for (int tt = 0; tt < TT; ++tt) acc[tt][co] = bv;
    }

    for (int ci = 0; ci < CIN; ++ci) {          // rolled
        float xv[11];
#pragma unroll
        for (int q = 0; q < 11; ++q)
            xv[q] = Xl[ci][4 * h + q][b];       // conflict-free ds_read
        const float* wc = wk + ci * CO;
#pragma unroll
        for (int d = 0; d < 8; ++d) {
            const float* wd = wc + d * CIN * CO;
            float wv[CO];
#pragma unroll
            for (int cq = 0; cq < CO; cq += 4) {
                const float4 w4 = *reinterpret_cast<const float4*>(wd + cq);
                wv[cq + 0] = w4.x; wv[cq + 1] = w4.y;
                wv[cq + 2] = w4.z; wv[cq + 3] = w4.w;
            }
#pragma unroll
            for (int tt = 0; tt < TT; ++tt) {
                const float xx = xv[7 + tt - d];   // row 4h + (7+tt-d); k = k0+4d
#pragma unroll
                for (int co = 0; co < CO; ++co)
                    acc[tt][co] = fmaf(xx, wv[co], acc[tt][co]);
            }
        }
    }

    float* yb = y + (size_t)blockIdx.y * sfc_ystride;
#pragma unroll
    for (int tt = 0; tt < TT; ++tt) {
        const int t = t0 + 4 * tt;
        if (t < Lout) {
#pragma unroll
            for (int co = 0; co < CO; ++co)
                yb[((size_t)co * Lout + t) * 64 + b] = ftanh(acc[tt][co]);
        }
    }
}

// ---------------- conv4 specialized (r9 core): COUT=1, SGPR weights, imm offsets ----
template<int CIN, int TT, bool GUARD>
__device__ __forceinline__ void conv4_core(
    const float* __restrict__ xs, int cistride, int Lin, int jhi0,
    const float (&wreg)[8][CIN], float (&acc)[TT])
{
    constexpr int NJ = TT + 7;
    const int jlo = jhi0 - 7;
    const float* xsj = xs + (ptrdiff_t)jlo * 64;
    for (int ci = 0; ci < CIN; ++ci) {       // rolled
        float xv[NJ];
        if constexpr (GUARD) {
            const float* xpc = xs + (size_t)ci * cistride;
#pragma unroll
            for (int q = 0; q < NJ; ++q) {
                const int j = jlo + q;
                xv[q] = (j >= 0 && j < Lin) ? xpc[(ptrdiff_t)j * 64] : 0.f;
            }
        } else {
            const float* xpc = xsj + (size_t)ci * cistride;
#pragma unroll
            for (int q = 0; q < NJ; ++q)
                xv[q] = xpc[q * 64];
        }
#pragma unroll
        for (int d = 0; d < 8; ++d)
#pragma unroll
            for (int tt = 0; tt < TT; ++tt)
                acc[tt] = fmaf(xv[7 + tt - d], wreg[d][ci], acc[tt]);
    }
}

template<int CIN, int TT, int MINW>
__global__ __launch_bounds__(256, MINW) void convt4_kernel(
    const float* __restrict__ x, size_t sfc_xstride, int cistride,
    const float* __restrict__ wp, int sfc_wstride,
    const float* __restrict__ bias, int sfc_bstride,
    float* __restrict__ y, size_t sfc_ystride, int Lin, int Lout)
{
    const int b = threadIdx.x & 63;
    const int widx = __builtin_amdgcn_readfirstlane(threadIdx.x >> 6);
    const int t0 = blockIdx.x * (4 * TT) + widx;
    if (t0 >= Lout) return;
    const int k0   = (t0 + 16) & 3;
    const int jhi0 = (t0 + 16) >> 2;
    const float* wk = wp + blockIdx.y * sfc_wstride + k0 * (8 * CIN);
    float wreg[8][CIN];
#pragma unroll
    for (int d = 0; d < 8; ++d)
#pragma unroll
        for (int ci = 0; ci < CIN; ++ci)
            wreg[d][ci] = wk[d * CIN + ci];
    const float bv = bias[blockIdx.y * sfc_bstride];
    float acc[TT];
#pragma unroll
    for (int tt = 0; tt < TT; ++tt) acc[tt] = bv;
    const float* xs = x + (size_t)blockIdx.y * sfc_xstride + b;

    const bool interior = (jhi0 >= 7) && (jhi0 + TT - 1 < Lin);
    if (interior) conv4_core<CIN, TT, false>(xs, cistride, Lin, jhi0, wreg, acc);
    else          conv4_core<CIN, TT, true >(xs, cistride, Lin, jhi0, wreg, acc);

    float* yb = y + (size_t)blockIdx.y * sfc_ystride;
#pragma unroll
    for (int tt = 0; tt < TT; ++tt) {
        const int t = t0 + 4 * tt;
        if (t < Lout) yb[(size_t)t * 64 + b] = ftanh(acc[tt]);
    }
}

// ---------------- Final gather + NearestNeighbouring (rolling window) ----------------
__global__ __launch_bounds__(256) void final_kernel(
    const float* __restrict__ d0, const float* __restrict__ d1,
    const float* __restrict__ nn_w, const float* __restrict__ nn_b,
    const int* __restrict__ oi,
    float* __restrict__ out)
{
    __shared__ float zl[16][65];
    const int tid = threadIdx.x;
    const int b = tid & 63;
    const int widx = __builtin_amdgcn_readfirstlane(tid >> 6);
    const int nblk = blockIdx.x * 16;
    const int n0 = nblk + widx * 4;

    float g[2][6];
#pragma unroll
    for (int s = 0; s < 2; ++s) {
        const float* dd = s ? d1 : d0;
        const int* ois = oi + s * NNODES;
#pragma unroll
        for (int q = 0; q < 6; ++q) {
            int pos = n0 - 1 + q;
            pos = pos < 0 ? 0 : (pos > NNODES - 1 ? NNODES - 1 : pos);
            g[s][q] = dd[(size_t)ois[pos] * 64 + b];
        }
    }
#pragma unroll
    for (int nn = 0; nn < 4; ++nn) {
        const int n = n0 + nn;
        float z = 0.f;
#pragma unroll
        for (int s = 0; s < 2; ++s) {
            const float* wv = nn_w + (size_t)(s * NNODES + n) * 3;
            z += ftanh(wv[0] * g[s][nn] + wv[1] * g[s][nn + 1]
                     + wv[2] * g[s][nn + 2] + nn_b[s * NNODES + n]);
        }
        zl[widx * 4 + nn][b] = ftanh(z);
    }
    __syncthreads();
    const int bq = tid >> 2;
    const int nq = tid & 3;
    float4 v;
    v.x = zl[nq * 4 + 0][bq];
    v.y = zl[nq * 4 + 1][bq];
    v.z = zl[nq * 4 + 2][bq];
    v.w = zl[nq * 4 + 3][bq];
    *reinterpret_cast<float4*>(out + (size_t)bq * NNODES + nblk + nq * 4) = v;
}

extern "C" void kernel_launch(void* const* d_in, const int* in_sizes, int n_in,
                              void* d_out, int out_size, void* d_ws, size_t ws_size,
                              hipStream_t stream)
{
    const float* x     = (const float*)d_in[0];
    const float* fc_w1 = (const float*)d_in[1];
    const float* fc_b1 = (const float*)d_in[2];
    const float* fc_w2 = (const float*)d_in[3];
    const float* fc_b2 = (const float*)d_in[4];
    const float* nn_w  = (const float*)d_in[5];
    const float* nn_b  = (const float*)d_in[6];
    const int* ord_i   = (const int*)d_in[7];
    const float* conv_w1 = (const float*)d_in[10];
    const float* conv_b1 = (const float*)d_in[11];
    const float* conv_w2 = (const float*)d_in[12];
    const float* conv_b2 = (const float*)d_in[13];
    const float* conv_w3 = (const float*)d_in[14];
    const float* conv_b3 = (const float*)d_in[15];
    const float* conv_w4 = (const float*)d_in[16];
    const float* conv_b4 = (const float*)d_in[17];
    float* out = (float*)d_out;

    const size_t SZ_Y1 = (size_t)16 * 1601 * 64;
    const size_t SZ_Y2 = (size_t)16 * 6401 * 64;
    const size_t SZ_Y3 = (size_t)8  * 25601 * 64;
    const size_t SZ_Y4 = (size_t)NNODES * 64;

    const size_t need22 = 56638976ull * 4;   // NS=2, NY3=2
    const size_t need21 = 43531264ull * 4;   // NS=2, NY3=1
    int NS = 1, NY3 = 1;
    if (ws_size >= need22)      { NS = 2; NY3 = 2; }
    else if (ws_size >= need21) { NS = 2; NY3 = 1; }

    float* ws  = (float*)d_ws;
    float* h1t = ws;
    float* h2t = h1t + 65536;
    float* y1  = h2t + 821248;
    float* y2  = y1  + (size_t)NS * SZ_Y1;
    float* y3  = y2  + (size_t)NS * SZ_Y2;
    float* y4  = y3  + (size_t)NY3 * SZ_Y3;
    float* wp1 = y4  + 2 * SZ_Y4;
    float* wp2 = wp1 + 16384;
    float* wp3 = wp2 + 16384;
    float* wp4 = wp3 + 8192;
    float* part = y3;   // fc2 partials alias y3 (consumed before convs)

    fc1_kernel<<<dim3(256),  dim3(256), 0, stream>>>(x, fc_w1, fc_b1, h1t);
    fc2_gemm_kernel<<<dim3(401, 4), dim3(128), 0, stream>>>(h1t, fc_w2, part);
    fc2_reduce_kernel<<<dim3(3208), dim3(256), 0, stream>>>(part, fc_b2, h2t);
    pack_all_kernel<<<dim3(162), dim3(256), 0, stream>>>(
        conv_w1, conv_w2, conv_w3, conv_w4, wp1, wp2, wp3, wp4);

    for (int s0 = 0; s0 < 2; s0 += NS) {
        // conv1: 16->16, 401 -> 1601; TT=1, co-split 2; JSTR=128
        convt3_kernel<16, 16, 1, 2, 8, 128><<<dim3(401, NS, 2), dim3(256), 0, stream>>>(
            h2t + s0 * 64, 64, 401 * 128,
            wp1 + s0 * 8192, 8192, conv_b1 + s0 * 16, 16,
            y1, SZ_Y1, 401, 1601);
        // conv2: 16->16, 1601 -> 6401; TT=4, co-split 2; JSTR=64
        convt3_kernel<16, 16, 4, 2, 6, 64><<<dim3(401, NS, 2), dim3(256), 0, stream>>>(
            y1, SZ_Y1, 1601 * 64,
            wp2 + s0 * 8192, 8192, conv_b2 + s0 * 16, 16,
            y2, SZ_Y2, 1601, 6401);
        if (NY3 == 1) {
            for (int s = s0; s < s0 + NS; ++s) {
                const float* xin = y2 + (size_t)(NS == 2 ? (s - s0) : 0) * SZ_Y2;
                convt3_lds_kernel<<<dim3(801, 1), dim3(512), 0, stream>>>(
                    xin, 0,
                    wp3 + s * 4096, 0, conv_b3 + s * 8, 0,
                    y3, 0, 6401, 25601);
                convt4_kernel<8, 16, 8><<<dim3(1600, 1), dim3(256), 0, stream>>>(
                    y3, 0, 25601 * 64,
                    wp4 + s * 256, 0, conv_b4 + s, 0,
                    y4 + (size_t)s * SZ_Y4, 0, 25601, 102400);
            }
        }
    }
    if (NY3 == 2) {
        // conv3: LDS-staged, both sfc in one dispatch (801 x 2 blocks, 512 thr)
        convt3_lds_kernel<<<dim3(801, 2), dim3(512), 0, stream>>>(
            y2, SZ_Y2,
            wp3, 4096, conv_b3, 8,
            y3, SZ_Y3, 6401, 25601);
        // conv4: 8->1, 25601 -> 102400; TT=16, both sfc
        convt4_kernel<8, 16, 8><<<dim3(1600, 2), dim3(256), 0, stream>>>(
            y3, SZ_Y3, 25601 * 64,
            wp4, 256, conv_b4, 1,
            y4, SZ_Y4, 25601, 102400);
    }

    final_kernel<<<dim3(6400), dim3(256), 0, stream>>>(
        y4, y4 + SZ_Y4, nn_w, nn_b, ord_i, out);
}

// Round 14
// 293.121 us; speedup vs baseline: 1.0863x; 1.0863x over previous
//
#include <hip/hip_runtime.h>

#define NNODES 102400

__device__ __forceinline__ float ftanh(float x) {
    float a = fabsf(x);
    float e = __expf(-2.0f * a);
    float t = (1.0f - e) / (1.0f + e);
    return copysignf(t, x);
}

// ---------------- FC1 ----------------
__global__ __launch_bounds__(256) void fc1_kernel(
    const float* __restrict__ x, const float* __restrict__ w1,
    const float* __restrict__ b1, float* __restrict__ h1t)
{
    const int b = threadIdx.x & 63;
    const int o = blockIdx.x * 4 + __builtin_amdgcn_readfirstlane(threadIdx.x >> 6);
    const float* xr = x + b * 128;
    const float* wr = w1 + o * 128;
    float acc = 0.f;
#pragma unroll
    for (int k = 0; k < 128; ++k) acc = fmaf(xr[k], wr[k], acc);
    h1t[o * 64 + b] = ftanh(acc + b1[o]);
}

// ---------------- FC2 as LDS-tiled GEMM ----------------
__global__ __launch_bounds__(128) void fc2_gemm_kernel(
    const float* __restrict__ h1t,   // [1024][64]
    const float* __restrict__ w2,    // [12832][1024]
    float* __restrict__ part)        // [4][12832][64]
{
    __shared__ float Wl[32][68];
    __shared__ float Hl[64][64];
    const int t  = threadIdx.x;
    const int o0 = blockIdx.x * 32;
    const int ks = blockIdx.y;
    const int ob = (t >> 4) * 4;
    const int b4 = (t & 15) * 4;

    float acc[4][4] = {};
    const int kbase = ks * 256;
#pragma unroll 1
    for (int kt = 0; kt < 4; ++kt) {
        const int k0 = kbase + kt * 64;
        {
            const int row = t >> 2;
            const int c0  = (t & 3) * 4;
            const float* src = w2 + (size_t)(o0 + row) * 1024 + k0;
#pragma unroll
            for (int i = 0; i < 4; ++i) {
                const float4 v = *reinterpret_cast<const float4*>(src + c0 + 16 * i);
                *reinterpret_cast<float4*>(&Wl[row][c0 + 16 * i]) = v;
            }
        }
        {
            const float* src = h1t + (size_t)k0 * 64;
            float* dst = &Hl[0][0];
#pragma unroll
            for (int i = 0; i < 8; ++i) {
                const int f4 = t + 128 * i;
                const float4 v = *reinterpret_cast<const float4*>(src + f4 * 4);
                *reinterpret_cast<float4*>(dst + f4 * 4) = v;
            }
        }
        __syncthreads();
#pragma unroll
        for (int kk = 0; kk < 16; ++kk) {
            const int k4 = kk * 4;
            float wv[4][4], hv[4][4];
#pragma unroll
            for (int i = 0; i < 4; ++i) {
                const float4 v = *reinterpret_cast<const float4*>(&Wl[ob + i][k4]);
                wv[i][0] = v.x; wv[i][1] = v.y; wv[i][2] = v.z; wv[i][3] = v.w;
            }
#pragma unroll
            for (int j = 0; j < 4; ++j) {
                const float4 v = *reinterpret_cast<const float4*>(&Hl[k4 + j][b4]);
                hv[j][0] = v.x; hv[j][1] = v.y; hv[j][2] = v.z; hv[j][3] = v.w;
            }
#pragma unroll
            for (int i = 0; i < 4; ++i)
#pragma unroll
                for (int j = 0; j < 4; ++j)
#pragma unroll
                    for (int jb = 0; jb < 4; ++jb)
                        acc[i][jb] = fmaf(wv[i][j], hv[j][jb], acc[i][jb]);
        }
        __syncthreads();
    }
    float* pb = part + ((size_t)ks * 12832 + o0) * 64;
#pragma unroll
    for (int i = 0; i < 4; ++i) {
        const float4 v = make_float4(acc[i][0], acc[i][1], acc[i][2], acc[i][3]);
        *reinterpret_cast<float4*>(pb + (size_t)(ob + i) * 64 + b4) = v;
    }
}

__global__ __launch_bounds__(256) void fc2_reduce_kernel(
    const float* __restrict__ part, const float* __restrict__ b2,
    float* __restrict__ h2t)
{
    const int idx = blockIdx.x * 256 + threadIdx.x;
    const int o = idx >> 6;
    const float s = part[idx] + part[821248 + idx]
                  + part[1642496 + idx] + part[2463744 + idx];
    h2t[idx] = ftanh(s + b2[o]);
}

// ---------------- weight pre-pack: w[i][ci][co][k] -> wp[i][k0][d][ci][co] ----------------
__device__ __forceinline__ void pack_one(const float* __restrict__ w, float* __restrict__ wp,
                                         int CIN, int COUT, int idx)
{
    const int k = idx & 31;
    int r = idx >> 5;
    const int co = r % COUT; r /= COUT;
    const int ci = r % CIN;
    const int i  = r / CIN;
    const int k0 = k & 3, d = k >> 2;
    wp[(((i * 4 + k0) * 8 + d) * CIN + ci) * COUT + co] = w[idx];
}

__global__ __launch_bounds__(256) void pack_all_kernel(
    const float* __restrict__ w1, const float* __restrict__ w2,
    const float* __restrict__ w3, const float* __restrict__ w4,
    float* __restrict__ wp1, float* __restrict__ wp2,
    float* __restrict__ wp3, float* __restrict__ wp4)
{
    const int idx = blockIdx.x * 256 + threadIdx.x;
    if (idx < 16384)       pack_one(w1, wp1, 16, 16, idx);
    else if (idx < 32768)  pack_one(w2, wp2, 16, 16, idx - 16384);
    else if (idx < 40960)  pack_one(w3, wp3, 16,  8, idx - 32768);
    else if (idx < 41472)  pack_one(w4, wp4,  8,  1, idx - 40960);
}

// ---------------- ConvTranspose1d core (r9/r10 known-good: rolled ci, imm-offset) ---
template<int CIN, int CPG, int TT, int JSTR, bool GUARD>
__device__ __forceinline__ void conv_core(
    const float* __restrict__ xs, int cistride, int Lin,
    const float* __restrict__ wk, int wco, int jhi0, float (&acc)[TT][CPG])
{
    constexpr int NJ = TT + 7;
    const int jlo = jhi0 - 7;
    const float* xsj = xs + (ptrdiff_t)jlo * JSTR;
    for (int ci = 0; ci < CIN; ++ci) {               // rolled (r7/r8: unroll regresses)
        float xv[NJ];
        if constexpr (GUARD) {
            const float* xpc = xs + (size_t)ci * cistride;
#pragma unroll
            for (int q = 0; q < NJ; ++q) {
                const int j = jlo + q;
                xv[q] = (j >= 0 && j < Lin) ? xpc[(ptrdiff_t)j * JSTR] : 0.f;
            }
        } else {
            const float* xpc = xsj + (size_t)ci * cistride;
#pragma unroll
            for (int q = 0; q < NJ; ++q)
                xv[q] = xpc[q * JSTR];               // imm-offset loads
        }
        const float* wc = wk + ci * wco;
#pragma unroll
        for (int d = 0; d < 8; ++d) {
            const float* wd = wc + d * CIN * wco;
            float wv[CPG];
            if constexpr ((CPG & 3) == 0) {
#pragma unroll
                for (int cq = 0; cq < CPG; cq += 4) {
                    const float4 w4 = *reinterpret_cast<const float4*>(wd + cq);
                    wv[cq + 0] = w4.x; wv[cq + 1] = w4.y;
                    wv[cq + 2] = w4.z; wv[cq + 3] = w4.w;
                }
            } else {
#pragma unroll
                for (int co = 0; co < CPG; ++co) wv[co] = wd[co];
            }
#pragma unroll
            for (int tt = 0; tt < TT; ++tt) {
                const float xx = xv[7 + tt - d];
#pragma unroll
                for (int co = 0; co < CPG; ++co)
                    acc[tt][co] = fmaf(xx, wv[co], acc[tt][co]);
            }
        }
    }
}

template<int CIN, int COUT, int TT, int COG, int MINW, int JSTR>
__global__ __launch_bounds__(256, MINW) void convt3_kernel(
    const float* __restrict__ x, size_t sfc_xstride, int cistride,
    const float* __restrict__ wp, int sfc_wstride,
    const float* __restrict__ bias, int sfc_bstride,
    float* __restrict__ y, size_t sfc_ystride,
    int Lin, int Lout)
{
    constexpr int CPG = COUT / COG;
    const int b = threadIdx.x & 63;
    const int widx = __builtin_amdgcn_readfirstlane(threadIdx.x >> 6);
    const int t0 = blockIdx.x * (4 * TT) + widx;
    if (t0 >= Lout) return;
    const int cb = blockIdx.z * CPG;
    const int k0   = (t0 + 16) & 3;
    const int jhi0 = (t0 + 16) >> 2;
    const float* xs = x + (size_t)blockIdx.y * sfc_xstride + b;
    const float* wk = wp + blockIdx.y * sfc_wstride + k0 * (8 * CIN * COUT) + cb;
    const float* bs = bias + blockIdx.y * sfc_bstride + cb;

    float acc[TT][CPG];
#pragma unroll
    for (int co = 0; co < CPG; ++co) {
        const float bv = bs[co];
#pragma unroll
        for (int tt = 0; tt < TT; ++tt) acc[tt][co] = bv;
    }

    const bool interior = (jhi0 >= 7) && (jhi0 + TT - 1 < Lin);
    if (interior)
        conv_core<CIN, CPG, TT, JSTR, false>(xs, cistride, Lin, wk, COUT, jhi0, acc);
    else
        conv_core<CIN, CPG, TT, JSTR, true >(xs, cistride, Lin, wk, COUT, jhi0, acc);

#pragma unroll
    for (int tt = 0; tt < TT; ++tt) {
        const int t = t0 + 4 * tt;
        if (t < Lout) {
#pragma unroll
            for (int co = 0; co < CPG; ++co)
                y[(size_t)blockIdx.y * sfc_ystride + ((size_t)(cb + co) * Lout + t) * 64 + b] =
                    ftanh(acc[tt][co]);
        }
    }
}

// ---------------- conv4 specialized (r9 core): COUT=1, SGPR weights, imm offsets ----
template<int CIN, int TT, bool GUARD>
__device__ __forceinline__ void conv4_core(
    const float* __restrict__ xs, int cistride, int Lin, int jhi0,
    const float (&wreg)[8][CIN], float (&acc)[TT])
{
    constexpr int NJ = TT + 7;
    const int jlo = jhi0 - 7;
    const float* xsj = xs + (ptrdiff_t)jlo * 64;
    for (int ci = 0; ci < CIN; ++ci) {       // rolled
        float xv[NJ];
        if constexpr (GUARD) {
            const float* xpc = xs + (size_t)ci * cistride;
#pragma unroll
            for (int q = 0; q < NJ; ++q) {
                const int j = jlo + q;
                xv[q] = (j >= 0 && j < Lin) ? xpc[(ptrdiff_t)j * 64] : 0.f;
            }
        } else {
            const float* xpc = xsj + (size_t)ci * cistride;
#pragma unroll
            for (int q = 0; q < NJ; ++q)
                xv[q] = xpc[q * 64];
        }
#pragma unroll
        for (int d = 0; d < 8; ++d)
#pragma unroll
            for (int tt = 0; tt < TT; ++tt)
                acc[tt] = fmaf(xv[7 + tt - d], wreg[d][ci], acc[tt]);
    }
}

template<int CIN, int TT, int MINW>
__global__ __launch_bounds__(256, MINW) void convt4_kernel(
    const float* __restrict__ x, size_t sfc_xstride, int cistride,
    const float* __restrict__ wp, int sfc_wstride,
    const float* __restrict__ bias, int sfc_bstride,
    float* __restrict__ y, size_t sfc_ystride, int Lin, int Lout)
{
    const int b = threadIdx.x & 63;
    const int widx = __builtin_amdgcn_readfirstlane(threadIdx.x >> 6);
    const int t0 = blockIdx.x * (4 * TT) + widx;
    if (t0 >= Lout) return;
    const int k0   = (t0 + 16) & 3;
    const int jhi0 = (t0 + 16) >> 2;
    const float* wk = wp + blockIdx.y * sfc_wstride + k0 * (8 * CIN);
    float wreg[8][CIN];
#pragma unroll
    for (int d = 0; d < 8; ++d)
#pragma unroll
        for (int ci = 0; ci < CIN; ++ci)
            wreg[d][ci] = wk[d * CIN + ci];
    const float bv = bias[blockIdx.y * sfc_bstride];
    float acc[TT];
#pragma unroll
    for (int tt = 0; tt < TT; ++tt) acc[tt] = bv;
    const float* xs = x + (size_t)blockIdx.y * sfc_xstride + b;

    const bool interior = (jhi0 >= 7) && (jhi0 + TT - 1 < Lin);
    if (interior) conv4_core<CIN, TT, false>(xs, cistride, Lin, jhi0, wreg, acc);
    else          conv4_core<CIN, TT, true >(xs, cistride, Lin, jhi0, wreg, acc);

    float* yb = y + (size_t)blockIdx.y * sfc_ystride;
#pragma unroll
    for (int tt = 0; tt < TT; ++tt) {
        const int t = t0 + 4 * tt;
        if (t < Lout) yb[(size_t)t * 64 + b] = ftanh(acc[tt]);
    }
}

// ---------------- Final gather + NearestNeighbouring (rolling window) ----------------
__global__ __launch_bounds__(256) void final_kernel(
    const float* __restrict__ d0, const float* __restrict__ d1,
    const float* __restrict__ nn_w, const float* __restrict__ nn_b,
    const int* __restrict__ oi,
    float* __restrict__ out)
{
    __shared__ float zl[16][65];
    const int tid = threadIdx.x;
    const int b = tid & 63;
    const int widx = __builtin_amdgcn_readfirstlane(tid >> 6);
    const int nblk = blockIdx.x * 16;
    const int n0 = nblk + widx * 4;

    float g[2][6];
#pragma unroll
    for (int s = 0; s < 2; ++s) {
        const float* dd = s ? d1 : d0;
        const int* ois = oi + s * NNODES;
#pragma unroll
        for (int q = 0; q < 6; ++q) {
            int pos = n0 - 1 + q;
            pos = pos < 0 ? 0 : (pos > NNODES - 1 ? NNODES - 1 : pos);
            g[s][q] = dd[(size_t)ois[pos] * 64 + b];
        }
    }
#pragma unroll
    for (int nn = 0; nn < 4; ++nn) {
        const int n = n0 + nn;
        float z = 0.f;
#pragma unroll
        for (int s = 0; s < 2; ++s) {
            const float* wv = nn_w + (size_t)(s * NNODES + n) * 3;
            z += ftanh(wv[0] * g[s][nn] + wv[1] * g[s][nn + 1]
                     + wv[2] * g[s][nn + 2] + nn_b[s * NNODES + n]);
        }
        zl[widx * 4 + nn][b] = ftanh(z);
    }
    __syncthreads();
    const int bq = tid >> 2;
    const int nq = tid & 3;
    float4 v;
    v.x = zl[nq * 4 + 0][bq];
    v.y = zl[nq * 4 + 1][bq];
    v.z = zl[nq * 4 + 2][bq];
    v.w = zl[nq * 4 + 3][bq];
    *reinterpret_cast<float4*>(out + (size_t)bq * NNODES + nblk + nq * 4) = v;
}

extern "C" void kernel_launch(void* const* d_in, const int* in_sizes, int n_in,
                              void* d_out, int out_size, void* d_ws, size_t ws_size,
                              hipStream_t stream)
{
    const float* x     = (const float*)d_in[0];
    const float* fc_w1 = (const float*)d_in[1];
    const float* fc_b1 = (const float*)d_in[2];
    const float* fc_w2 = (const float*)d_in[3];
    const float* fc_b2 = (const float*)d_in[4];
    const float* nn_w  = (const float*)d_in[5];
    const float* nn_b  = (const float*)d_in[6];
    const int* ord_i   = (const int*)d_in[7];
    const float* conv_w1 = (const float*)d_in[10];
    const float* conv_b1 = (const float*)d_in[11];
    const float* conv_w2 = (const float*)d_in[12];
    const float* conv_b2 = (const float*)d_in[13];
    const float* conv_w3 = (const float*)d_in[14];
    const float* conv_b3 = (const float*)d_in[15];
    const float* conv_w4 = (const float*)d_in[16];
    const float* conv_b4 = (const float*)d_in[17];
    float* out = (float*)d_out;

    const size_t SZ_Y1 = (size_t)16 * 1601 * 64;
    const size_t SZ_Y2 = (size_t)16 * 6401 * 64;
    const size_t SZ_Y3 = (size_t)8  * 25601 * 64;
    const size_t SZ_Y4 = (size_t)NNODES * 64;

    const size_t need22 = 56638976ull * 4;   // NS=2, NY3=2
    const size_t need21 = 43531264ull * 4;   // NS=2, NY3=1
    int NS = 1, NY3 = 1;
    if (ws_size >= need22)      { NS = 2; NY3 = 2; }
    else if (ws_size >= need21) { NS = 2; NY3 = 1; }

    float* ws  = (float*)d_ws;
    float* h1t = ws;
    float* h2t = h1t + 65536;
    float* y1  = h2t + 821248;
    float* y2  = y1  + (size_t)NS * SZ_Y1;
    float* y3  = y2  + (size_t)NS * SZ_Y2;
    float* y4  = y3  + (size_t)NY3 * SZ_Y3;
    float* wp1 = y4  + 2 * SZ_Y4;
    float* wp2 = wp1 + 16384;
    float* wp3 = wp2 + 16384;
    float* wp4 = wp3 + 8192;
    float* part = y3;   // fc2 partials alias y3 (consumed before convs)

    fc1_kernel<<<dim3(256),  dim3(256), 0, stream>>>(x, fc_w1, fc_b1, h1t);
    fc2_gemm_kernel<<<dim3(401, 4), dim3(128), 0, stream>>>(h1t, fc_w2, part);
    fc2_reduce_kernel<<<dim3(3208), dim3(256), 0, stream>>>(part, fc_b2, h2t);
    pack_all_kernel<<<dim3(162), dim3(256), 0, stream>>>(
        conv_w1, conv_w2, conv_w3, conv_w4, wp1, wp2, wp3, wp4);

    for (int s0 = 0; s0 < 2; s0 += NS) {
        // conv1: 16->16, 401 -> 1601; TT=1, co-split 2; JSTR=128
        convt3_kernel<16, 16, 1, 2, 8, 128><<<dim3(401, NS, 2), dim3(256), 0, stream>>>(
            h2t + s0 * 64, 64, 401 * 128,
            wp1 + s0 * 8192, 8192, conv_b1 + s0 * 16, 16,
            y1, SZ_Y1, 401, 1601);
        // conv2: 16->16, 1601 -> 6401; TT=4, co-split 2; JSTR=64
        convt3_kernel<16, 16, 4, 2, 8, 64><<<dim3(401, NS, 2), dim3(256), 0, stream>>>(
            y1, SZ_Y1, 1601 * 64,
            wp2 + s0 * 8192, 8192, conv_b2 + s0 * 16, 16,
            y2, SZ_Y2, 1601, 6401);
        if (NY3 == 1) {
            for (int s = s0; s < s0 + NS; ++s) {
                const float* xin = y2 + (size_t)(NS == 2 ? (s - s0) : 0) * SZ_Y2;
                convt3_kernel<16, 8, 4, 1, 8, 64><<<dim3(1601, 1, 1), dim3(256), 0, stream>>>(
                    xin, 0, 6401 * 64,
                    wp3 + s * 4096, 0, conv_b3 + s * 8, 0,
                    y3, 0, 6401, 25601);
                convt4_kernel<8, 16, 8><<<dim3(1600, 1), dim3(256), 0, stream>>>(
                    y3, 0, 25601 * 64,
                    wp4 + s * 256, 0, conv_b4 + s, 0,
                    y4 + (size_t)s * SZ_Y4, 0, 25601, 102400);
            }
        }
    }
    if (NY3 == 2) {
        // conv3: 16->8, 6401 -> 25601; TT=4, CPG=8 (no co-split), both sfc
        convt3_kernel<16, 8, 4, 1, 8, 64><<<dim3(1601, 2, 1), dim3(256), 0, stream>>>(
            y2, SZ_Y2, 6401 * 64,
            wp3, 4096, conv_b3, 8,
            y3, SZ_Y3, 6401, 25601);
        // conv4: 8->1, 25601 -> 102400; TT=16, both sfc
        convt4_kernel<8, 16, 8><<<dim3(1600, 2), dim3(256), 0, stream>>>(
            y3, SZ_Y3, 25601 * 64,
            wp4, 256, conv_b4, 1,
            y4, SZ_Y4, 25601, 102400);
    }

    final_kernel<<<dim3(6400), dim3(256), 0, stream>>>(
        y4, y4 + SZ_Y4, nn_w, nn_b, ord_i, out);
}

// Round 15
// 284.455 us; speedup vs baseline: 1.1194x; 1.0305x over previous
//
#include <hip/hip_runtime.h>

#define NNODES 102400

__device__ __forceinline__ float ftanh(float x) {
    float a = fabsf(x);
    float e = __expf(-2.0f * a);
    float t = (1.0f - e) / (1.0f + e);
    return copysignf(t, x);
}

// ---------------- FC1 ----------------
__global__ __launch_bounds__(256) void fc1_kernel(
    const float* __restrict__ x, const float* __restrict__ w1,
    const float* __restrict__ b1, float* __restrict__ h1t)
{
    const int b = threadIdx.x & 63;
    const int o = blockIdx.x * 4 + __builtin_amdgcn_readfirstlane(threadIdx.x >> 6);
    const float* xr = x + b * 128;
    const float* wr = w1 + o * 128;
    float acc = 0.f;
#pragma unroll
    for (int k = 0; k < 128; ++k) acc = fmaf(xr[k], wr[k], acc);
    h1t[o * 64 + b] = ftanh(acc + b1[o]);
}

// ---------------- FC2 as LDS-tiled GEMM ----------------
__global__ __launch_bounds__(128) void fc2_gemm_kernel(
    const float* __restrict__ h1t,   // [1024][64]
    const float* __restrict__ w2,    // [12832][1024]
    float* __restrict__ part)        // [4][12832][64]
{
    __shared__ float Wl[32][68];
    __shared__ float Hl[64][64];
    const int t  = threadIdx.x;
    const int o0 = blockIdx.x * 32;
    const int ks = blockIdx.y;
    const int ob = (t >> 4) * 4;
    const int b4 = (t & 15) * 4;

    float acc[4][4] = {};
    const int kbase = ks * 256;
#pragma unroll 1
    for (int kt = 0; kt < 4; ++kt) {
        const int k0 = kbase + kt * 64;
        {
            const int row = t >> 2;
            const int c0  = (t & 3) * 4;
            const float* src = w2 + (size_t)(o0 + row) * 1024 + k0;
#pragma unroll
            for (int i = 0; i < 4; ++i) {
                const float4 v = *reinterpret_cast<const float4*>(src + c0 + 16 * i);
                *reinterpret_cast<float4*>(&Wl[row][c0 + 16 * i]) = v;
            }
        }
        {
            const float* src = h1t + (size_t)k0 * 64;
            float* dst = &Hl[0][0];
#pragma unroll
            for (int i = 0; i < 8; ++i) {
                const int f4 = t + 128 * i;
                const float4 v = *reinterpret_cast<const float4*>(src + f4 * 4);
                *reinterpret_cast<float4*>(dst + f4 * 4) = v;
            }
        }
        __syncthreads();
#pragma unroll
        for (int kk = 0; kk < 16; ++kk) {
            const int k4 = kk * 4;
            float wv[4][4], hv[4][4];
#pragma unroll
            for (int i = 0; i < 4; ++i) {
                const float4 v = *reinterpret_cast<const float4*>(&Wl[ob + i][k4]);
                wv[i][0] = v.x; wv[i][1] = v.y; wv[i][2] = v.z; wv[i][3] = v.w;
            }
#pragma unroll
            for (int j = 0; j < 4; ++j) {
                const float4 v = *reinterpret_cast<const float4*>(&Hl[k4 + j][b4]);
                hv[j][0] = v.x; hv[j][1] = v.y; hv[j][2] = v.z; hv[j][3] = v.w;
            }
#pragma unroll
            for (int i = 0; i < 4; ++i)
#pragma unroll
                for (int j = 0; j < 4; ++j)
#pragma unroll
                    for (int jb = 0; jb < 4; ++jb)
                        acc[i][jb] = fmaf(wv[i][j], hv[j][jb], acc[i][jb]);
        }
        __syncthreads();
    }
    float* pb = part + ((size_t)ks * 12832 + o0) * 64;
#pragma unroll
    for (int i = 0; i < 4; ++i) {
        const float4 v = make_float4(acc[i][0], acc[i][1], acc[i][2], acc[i][3]);
        *reinterpret_cast<float4*>(pb + (size_t)(ob + i) * 64 + b4) = v;
    }
}

__global__ __launch_bounds__(256) void fc2_reduce_kernel(
    const float* __restrict__ part, const float* __restrict__ b2,
    float* __restrict__ h2t)
{
    const int idx = blockIdx.x * 256 + threadIdx.x;
    const int o = idx >> 6;
    const float s = part[idx] + part[821248 + idx]
                  + part[1642496 + idx] + part[2463744 + idx];
    h2t[idx] = ftanh(s + b2[o]);
}

// ---------------- weight pre-pack: w[i][ci][co][k] -> wp[i][k0][d][ci][co] ----------------
__device__ __forceinline__ void pack_one(const float* __restrict__ w, float* __restrict__ wp,
                                         int CIN, int COUT, int idx)
{
    const int k = idx & 31;
    int r = idx >> 5;
    const int co = r % COUT; r /= COUT;
    const int ci = r % CIN;
    const int i  = r / CIN;
    const int k0 = k & 3, d = k >> 2;
    wp[(((i * 4 + k0) * 8 + d) * CIN + ci) * COUT + co] = w[idx];
}

__global__ __launch_bounds__(256) void pack_all_kernel(
    const float* __restrict__ w1, const float* __restrict__ w2,
    const float* __restrict__ w3, const float* __restrict__ w4,
    float* __restrict__ wp1, float* __restrict__ wp2,
    float* __restrict__ wp3, float* __restrict__ wp4)
{
    const int idx = blockIdx.x * 256 + threadIdx.x;
    if (idx < 16384)       pack_one(w1, wp1, 16, 16, idx);
    else if (idx < 32768)  pack_one(w2, wp2, 16, 16, idx - 16384);
    else if (idx < 40960)  pack_one(w3, wp3, 16,  8, idx - 32768);
    else if (idx < 41472)  pack_one(w4, wp4,  8,  1, idx - 40960);
}

// ---------------- ConvTranspose1d core (measured-best r9: rolled ci, imm-offset) ----
template<int CIN, int CPG, int TT, int JSTR, bool GUARD>
__device__ __forceinline__ void conv_core(
    const float* __restrict__ xs, int cistride, int Lin,
    const float* __restrict__ wk, int wco, int jhi0, float (&acc)[TT][CPG])
{
    constexpr int NJ = TT + 7;
    const int jlo = jhi0 - 7;
    const float* xsj = xs + (ptrdiff_t)jlo * JSTR;
    for (int ci = 0; ci < CIN; ++ci) {               // rolled (unroll regresses: r7/r8)
        float xv[NJ];
        if constexpr (GUARD) {
            const float* xpc = xs + (size_t)ci * cistride;
#pragma unroll
            for (int q = 0; q < NJ; ++q) {
                const int j = jlo + q;
                xv[q] = (j >= 0 && j < Lin) ? xpc[(ptrdiff_t)j * JSTR] : 0.f;
            }
        } else {
            const float* xpc = xsj + (size_t)ci * cistride;
#pragma unroll
            for (int q = 0; q < NJ; ++q)
                xv[q] = xpc[q * JSTR];               // imm-offset loads
        }
        const float* wc = wk + ci * wco;
#pragma unroll
        for (int d = 0; d < 8; ++d) {
            const float* wd = wc + d * CIN * wco;
            float wv[CPG];
            if constexpr ((CPG & 3) == 0) {
#pragma unroll
                for (int cq = 0; cq < CPG; cq += 4) {
                    const float4 w4 = *reinterpret_cast<const float4*>(wd + cq);
                    wv[cq + 0] = w4.x; wv[cq + 1] = w4.y;
                    wv[cq + 2] = w4.z; wv[cq + 3] = w4.w;
                }
            } else {
#pragma unroll
                for (int co = 0; co < CPG; ++co) wv[co] = wd[co];
            }
#pragma unroll
            for (int tt = 0; tt < TT; ++tt) {
                const float xx = xv[7 + tt - d];
#pragma unroll
                for (int co = 0; co < CPG; ++co)
                    acc[tt][co] = fmaf(xx, wv[co], acc[tt][co]);
            }
        }
    }
}

template<int CIN, int COUT, int TT, int COG, int MINW, int JSTR>
__global__ __launch_bounds__(256, MINW) void convt3_kernel(
    const float* __restrict__ x, size_t sfc_xstride, int cistride,
    const float* __restrict__ wp, int sfc_wstride,
    const float* __restrict__ bias, int sfc_bstride,
    float* __restrict__ y, size_t sfc_ystride,
    int Lin, int Lout)
{
    constexpr int CPG = COUT / COG;
    const int b = threadIdx.x & 63;
    const int widx = __builtin_amdgcn_readfirstlane(threadIdx.x >> 6);
    const int t0 = blockIdx.x * (4 * TT) + widx;
    if (t0 >= Lout) return;
    const int cb = blockIdx.z * CPG;
    const int k0   = (t0 + 16) & 3;
    const int jhi0 = (t0 + 16) >> 2;
    const float* xs = x + (size_t)blockIdx.y * sfc_xstride + b;
    const float* wk = wp + blockIdx.y * sfc_wstride + k0 * (8 * CIN * COUT) + cb;
    const float* bs = bias + blockIdx.y * sfc_bstride + cb;

    float acc[TT][CPG];
#pragma unroll
    for (int co = 0; co < CPG; ++co) {
        const float bv = bs[co];
#pragma unroll
        for (int tt = 0; tt < TT; ++tt) acc[tt][co] = bv;
    }

    const bool interior = (jhi0 >= 7) && (jhi0 + TT - 1 < Lin);
    if (interior)
        conv_core<CIN, CPG, TT, JSTR, false>(xs, cistride, Lin, wk, COUT, jhi0, acc);
    else
        conv_core<CIN, CPG, TT, JSTR, true >(xs, cistride, Lin, wk, COUT, jhi0, acc);

#pragma unroll
    for (int tt = 0; tt < TT; ++tt) {
        const int t = t0 + 4 * tt;
        if (t < Lout) {
#pragma unroll
            for (int co = 0; co < CPG; ++co)
                y[(size_t)blockIdx.y * sfc_ystride + ((size_t)(cb + co) * Lout + t) * 64 + b] =
                    ftanh(acc[tt][co]);
        }
    }
}

// ---------------- conv4 specialized: COUT=1, SGPR weights, imm offsets ----------
template<int CIN, int TT, bool GUARD>
__device__ __forceinline__ void conv4_core(
    const float* __restrict__ xs, int cistride, int Lin, int jhi0,
    const float (&wreg)[8][CIN], float (&acc)[TT])
{
    constexpr int NJ = TT + 7;
    const int jlo = jhi0 - 7;
    const float* xsj = xs + (ptrdiff_t)jlo * 64;
    for (int ci = 0; ci < CIN; ++ci) {       // rolled
        float xv[NJ];
        if constexpr (GUARD) {
            const float* xpc = xs + (size_t)ci * cistride;
#pragma unroll
            for (int q = 0; q < NJ; ++q) {
                const int j = jlo + q;
                xv[q] = (j >= 0 && j < Lin) ? xpc[(ptrdiff_t)j * 64] : 0.f;
            }
        } else {
            const float* xpc = xsj + (size_t)ci * cistride;
#pragma unroll
            for (int q = 0; q < NJ; ++q)
                xv[q] = xpc[q * 64];                 // imm-offset loads
        }
#pragma unroll
        for (int d = 0; d < 8; ++d)
#pragma unroll
            for (int tt = 0; tt < TT; ++tt)
                acc[tt] = fmaf(xv[7 + tt - d], wreg[d][ci], acc[tt]);
    }
}

template<int CIN, int TT, int MINW>
__global__ __launch_bounds__(256, MINW) void convt4_kernel(
    const float* __restrict__ x, size_t sfc_xstride, int cistride,
    const float* __restrict__ wp, int sfc_wstride,
    const float* __restrict__ bias, int sfc_bstride,
    float* __restrict__ y, size_t sfc_ystride, int Lin, int Lout)
{
    const int b = threadIdx.x & 63;
    const int widx = __builtin_amdgcn_readfirstlane(threadIdx.x >> 6);
    const int t0 = blockIdx.x * (4 * TT) + widx;
    if (t0 >= Lout) return;
    const int k0   = (t0 + 16) & 3;
    const int jhi0 = (t0 + 16) >> 2;
    const float* wk = wp + blockIdx.y * sfc_wstride + k0 * (8 * CIN);
    float wreg[8][CIN];
#pragma unroll
    for (int d = 0; d < 8; ++d)
#pragma unroll
        for (int ci = 0; ci < CIN; ++ci)
            wreg[d][ci] = wk[d * CIN + ci];
    const float bv = bias[blockIdx.y * sfc_bstride];
    float acc[TT];
#pragma unroll
    for (int tt = 0; tt < TT; ++tt) acc[tt] = bv;
    const float* xs = x + (size_t)blockIdx.y * sfc_xstride + b;

    const bool interior = (jhi0 >= 7) && (jhi0 + TT - 1 < Lin);
    if (interior) conv4_core<CIN, TT, false>(xs, cistride, Lin, jhi0, wreg, acc);
    else          conv4_core<CIN, TT, true >(xs, cistride, Lin, jhi0, wreg, acc);

    float* yb = y + (size_t)blockIdx.y * sfc_ystride;
#pragma unroll
    for (int tt = 0; tt < TT; ++tt) {
        const int t = t0 + 4 * tt;
        if (t < Lout) yb[(size_t)t * 64 + b] = ftanh(acc[tt]);
    }
}

// ---------------- Final gather + NearestNeighbouring ----------------
// 4 nodes/wave gathers; LDS transpose; store mapping writes full 64B lines.
__global__ __launch_bounds__(256) void final_kernel(
    const float* __restrict__ d0, const float* __restrict__ d1,
    const float* __restrict__ nn_w, const float* __restrict__ nn_b,
    const int* __restrict__ mi, const int* __restrict__ oi, const int* __restrict__ pi,
    float* __restrict__ out)
{
    __shared__ float zl[16][65];
    const int tid = threadIdx.x;
    const int b = tid & 63;
    const int widx = __builtin_amdgcn_readfirstlane(tid >> 6);
    const int nblk = blockIdx.x * 16;
    const int n0 = nblk + widx * 4;

    float g[2][4][3];
#pragma unroll
    for (int s = 0; s < 2; ++s) {
        const float* dd = s ? d1 : d0;
        const int off = s * NNODES;
#pragma unroll
        for (int nn = 0; nn < 4; ++nn) {
            const int n = off + n0 + nn;
            g[s][nn][0] = dd[(size_t)mi[n] * 64 + b];
            g[s][nn][1] = dd[(size_t)oi[n] * 64 + b];
            g[s][nn][2] = dd[(size_t)pi[n] * 64 + b];
        }
    }
#pragma unroll
    for (int nn = 0; nn < 4; ++nn) {
        const int n = n0 + nn;
        float z = 0.f;
#pragma unroll
        for (int s = 0; s < 2; ++s) {
            const float* wv = nn_w + (size_t)(s * NNODES + n) * 3;
            z += ftanh(wv[0] * g[s][nn][0] + wv[1] * g[s][nn][1]
                     + wv[2] * g[s][nn][2] + nn_b[s * NNODES + n]);
        }
        zl[widx * 4 + nn][b] = ftanh(z);
    }
    __syncthreads();
    const int bq = tid >> 2;
    const int nq = tid & 3;
    float4 v;
    v.x = zl[nq * 4 + 0][bq];
    v.y = zl[nq * 4 + 1][bq];
    v.z = zl[nq * 4 + 2][bq];
    v.w = zl[nq * 4 + 3][bq];
    *reinterpret_cast<float4*>(out + (size_t)bq * NNODES + nblk + nq * 4) = v;
}

extern "C" void kernel_launch(void* const* d_in, const int* in_sizes, int n_in,
                              void* d_out, int out_size, void* d_ws, size_t ws_size,
                              hipStream_t stream)
{
    const float* x     = (const float*)d_in[0];
    const float* fc_w1 = (const float*)d_in[1];
    const float* fc_b1 = (const float*)d_in[2];
    const float* fc_w2 = (const float*)d_in[3];
    const float* fc_b2 = (const float*)d_in[4];
    const float* nn_w  = (const float*)d_in[5];
    const float* nn_b  = (const float*)d_in[6];
    const int* ord_i   = (const int*)d_in[7];
    const int* minus_i = (const int*)d_in[8];
    const int* plus_i  = (const int*)d_in[9];
    const float* conv_w1 = (const float*)d_in[10];
    const float* conv_b1 = (const float*)d_in[11];
    const float* conv_w2 = (const float*)d_in[12];
    const float* conv_b2 = (const float*)d_in[13];
    const float* conv_w3 = (const float*)d_in[14];
    const float* conv_b3 = (const float*)d_in[15];
    const float* conv_w4 = (const float*)d_in[16];
    const float* conv_b4 = (const float*)d_in[17];
    float* out = (float*)d_out;

    const size_t SZ_Y1 = (size_t)16 * 1601 * 64;
    const size_t SZ_Y2 = (size_t)16 * 6401 * 64;
    const size_t SZ_Y3 = (size_t)8  * 25601 * 64;
    const size_t SZ_Y4 = (size_t)NNODES * 64;

    const size_t need22 = 56638976ull * 4;   // NS=2, NY3=2
    const size_t need21 = 43531264ull * 4;   // NS=2, NY3=1
    int NS = 1, NY3 = 1;
    if (ws_size >= need22)      { NS = 2; NY3 = 2; }
    else if (ws_size >= need21) { NS = 2; NY3 = 1; }

    float* ws  = (float*)d_ws;
    float* h1t = ws;
    float* h2t = h1t + 65536;
    float* y1  = h2t + 821248;
    float* y2  = y1  + (size_t)NS * SZ_Y1;
    float* y3  = y2  + (size_t)NS * SZ_Y2;
    float* y4  = y3  + (size_t)NY3 * SZ_Y3;
    float* wp1 = y4  + 2 * SZ_Y4;
    float* wp2 = wp1 + 16384;
    float* wp3 = wp2 + 16384;
    float* wp4 = wp3 + 8192;
    float* part = y3;   // fc2 partials alias y3 (consumed before convs)

    fc1_kernel<<<dim3(256),  dim3(256), 0, stream>>>(x, fc_w1, fc_b1, h1t);
    fc2_gemm_kernel<<<dim3(401, 4), dim3(128), 0, stream>>>(h1t, fc_w2, part);
    fc2_reduce_kernel<<<dim3(3208), dim3(256), 0, stream>>>(part, fc_b2, h2t);
    pack_all_kernel<<<dim3(162), dim3(256), 0, stream>>>(
        conv_w1, conv_w2, conv_w3, conv_w4, wp1, wp2, wp3, wp4);

    for (int s0 = 0; s0 < 2; s0 += NS) {
        // conv1: 16->16, 401 -> 1601; TT=1, co-split 2; JSTR=128
        convt3_kernel<16, 16, 1, 2, 8, 128><<<dim3(401, NS, 2), dim3(256), 0, stream>>>(
            h2t + s0 * 64, 64, 401 * 128,
            wp1 + s0 * 8192, 8192, conv_b1 + s0 * 16, 16,
            y1, SZ_Y1, 401, 1601);
        // conv2: 16->16, 1601 -> 6401; TT=4, co-split 2; MINW=6 (measured best)
        convt3_kernel<16, 16, 4, 2, 6, 64><<<dim3(401, NS, 2), dim3(256), 0, stream>>>(
            y1, SZ_Y1, 1601 * 64,
            wp2 + s0 * 8192, 8192, conv_b2 + s0 * 16, 16,
            y2, SZ_Y2, 1601, 6401);
        if (NY3 == 1) {
            for (int s = s0; s < s0 + NS; ++s) {
                const float* xin = y2 + (size_t)(NS == 2 ? (s - s0) : 0) * SZ_Y2;
                convt3_kernel<16, 8, 6, 2, 8, 64><<<dim3(1067, 1, 2), dim3(256), 0, stream>>>(
                    xin, 0, 6401 * 64,
                    wp3 + s * 4096, 0, conv_b3 + s * 8, 0,
                    y3, 0, 6401, 25601);
                convt4_kernel<8, 12, 8><<<dim3(2134, 1), dim3(256), 0, stream>>>(
                    y3, 0, 25601 * 64,
                    wp4 + s * 256, 0, conv_b4 + s, 0,
                    y4 + (size_t)s * SZ_Y4, 0, 25601, 102400);
            }
        }
    }
    if (NY3 == 2) {
        // conv3: 16->8, 6401 -> 25601; TT=6, co-split 2, both sfc (measured best)
        convt3_kernel<16, 8, 6, 2, 8, 64><<<dim3(1067, 2, 2), dim3(256), 0, stream>>>(
            y2, SZ_Y2, 6401 * 64,
            wp3, 4096, conv_b3, 8,
            y3, SZ_Y3, 6401, 25601);
        // conv4: 8->1, 25601 -> 102400; TT=12, MINW=8 (measured best)
        convt4_kernel<8, 12, 8><<<dim3(2134, 2), dim3(256), 0, stream>>>(
            y3, SZ_Y3, 25601 * 64,
            wp4, 256, conv_b4, 1,
            y4, SZ_Y4, 25601, 102400);
    }

    final_kernel<<<dim3(6400), dim3(256), 0, stream>>>(
        y4, y4 + SZ_Y4, nn_w, nn_b, minus_i, ord_i, plus_i, out);
}

// Round 16
// 280.159 us; speedup vs baseline: 1.1366x; 1.0153x over previous
//
#include <hip/hip_runtime.h>

#define NNODES 102400

__device__ __forceinline__ float ftanh(float x) {
    float a = fabsf(x);
    float e = __expf(-2.0f * a);
    float t = (1.0f - e) / (1.0f + e);
    return copysignf(t, x);
}

// ---------------- FC1 ----------------
__global__ __launch_bounds__(256) void fc1_kernel(
    const float* __restrict__ x, const float* __restrict__ w1,
    const float* __restrict__ b1, float* __restrict__ h1t)
{
    const int b = threadIdx.x & 63;
    const int o = blockIdx.x * 4 + __builtin_amdgcn_readfirstlane(threadIdx.x >> 6);
    const float* xr = x + b * 128;
    const float* wr = w1 + o * 128;
    float acc = 0.f;
#pragma unroll
    for (int k = 0; k < 128; ++k) acc = fmaf(xr[k], wr[k], acc);
    h1t[o * 64 + b] = ftanh(acc + b1[o]);
}

// ---------------- FC2 as LDS-tiled GEMM ----------------
__global__ __launch_bounds__(128) void fc2_gemm_kernel(
    const float* __restrict__ h1t,   // [1024][64]
    const float* __restrict__ w2,    // [12832][1024]
    float* __restrict__ part)        // [4][12832][64]
{
    __shared__ float Wl[32][68];
    __shared__ float Hl[64][64];
    const int t  = threadIdx.x;
    const int o0 = blockIdx.x * 32;
    const int ks = blockIdx.y;
    const int ob = (t >> 4) * 4;
    const int b4 = (t & 15) * 4;

    float acc[4][4] = {};
    const int kbase = ks * 256;
#pragma unroll 1
    for (int kt = 0; kt < 4; ++kt) {
        const int k0 = kbase + kt * 64;
        {
            const int row = t >> 2;
            const int c0  = (t & 3) * 4;
            const float* src = w2 + (size_t)(o0 + row) * 1024 + k0;
#pragma unroll
            for (int i = 0; i < 4; ++i) {
                const float4 v = *reinterpret_cast<const float4*>(src + c0 + 16 * i);
                *reinterpret_cast<float4*>(&Wl[row][c0 + 16 * i]) = v;
            }
        }
        {
            const float* src = h1t + (size_t)k0 * 64;
            float* dst = &Hl[0][0];
#pragma unroll
            for (int i = 0; i < 8; ++i) {
                const int f4 = t + 128 * i;
                const float4 v = *reinterpret_cast<const float4*>(src + f4 * 4);
                *reinterpret_cast<float4*>(dst + f4 * 4) = v;
            }
        }
        __syncthreads();
#pragma unroll
        for (int kk = 0; kk < 16; ++kk) {
            const int k4 = kk * 4;
            float wv[4][4], hv[4][4];
#pragma unroll
            for (int i = 0; i < 4; ++i) {
                const float4 v = *reinterpret_cast<const float4*>(&Wl[ob + i][k4]);
                wv[i][0] = v.x; wv[i][1] = v.y; wv[i][2] = v.z; wv[i][3] = v.w;
            }
#pragma unroll
            for (int j = 0; j < 4; ++j) {
                const float4 v = *reinterpret_cast<const float4*>(&Hl[k4 + j][b4]);
                hv[j][0] = v.x; hv[j][1] = v.y; hv[j][2] = v.z; hv[j][3] = v.w;
            }
#pragma unroll
            for (int i = 0; i < 4; ++i)
#pragma unroll
                for (int j = 0; j < 4; ++j)
#pragma unroll
                    for (int jb = 0; jb < 4; ++jb)
                        acc[i][jb] = fmaf(wv[i][j], hv[j][jb], acc[i][jb]);
        }
        __syncthreads();
    }
    float* pb = part + ((size_t)ks * 12832 + o0) * 64;
#pragma unroll
    for (int i = 0; i < 4; ++i) {
        const float4 v = make_float4(acc[i][0], acc[i][1], acc[i][2], acc[i][3]);
        *reinterpret_cast<float4*>(pb + (size_t)(ob + i) * 64 + b4) = v;
    }
}

__global__ __launch_bounds__(256) void fc2_reduce_kernel(
    const float* __restrict__ part, const float* __restrict__ b2,
    float* __restrict__ h2t)
{
    const int idx = blockIdx.x * 256 + threadIdx.x;
    const int o = idx >> 6;
    const float s = part[idx] + part[821248 + idx]
                  + part[1642496 + idx] + part[2463744 + idx];
    h2t[idx] = ftanh(s + b2[o]);
}

// ---------------- weight pre-pack: w[i][ci][co][k] -> wp[i][k0][d][ci][co] ----------------
__device__ __forceinline__ void pack_one(const float* __restrict__ w, float* __restrict__ wp,
                                         int CIN, int COUT, int idx)
{
    const int k = idx & 31;
    int r = idx >> 5;
    const int co = r % COUT; r /= COUT;
    const int ci = r % CIN;
    const int i  = r / CIN;
    const int k0 = k & 3, d = k >> 2;
    wp[(((i * 4 + k0) * 8 + d) * CIN + ci) * COUT + co] = w[idx];
}

__global__ __launch_bounds__(256) void pack_all_kernel(
    const float* __restrict__ w1, const float* __restrict__ w2,
    const float* __restrict__ w3, const float* __restrict__ w4,
    float* __restrict__ wp1, float* __restrict__ wp2,
    float* __restrict__ wp3, float* __restrict__ wp4)
{
    const int idx = blockIdx.x * 256 + threadIdx.x;
    if (idx < 16384)       pack_one(w1, wp1, 16, 16, idx);
    else if (idx < 32768)  pack_one(w2, wp2, 16, 16, idx - 16384);
    else if (idx < 40960)  pack_one(w3, wp3, 16,  8, idx - 32768);
    else if (idx < 41472)  pack_one(w4, wp4,  8,  1, idx - 40960);
}

// ---------------- ConvTranspose1d core (measured-best r9: rolled ci, imm-offset) ----
template<int CIN, int CPG, int TT, int JSTR, bool GUARD>
__device__ __forceinline__ void conv_core(
    const float* __restrict__ xs, int cistride, int Lin,
    const float* __restrict__ wk, int wco, int jhi0, float (&acc)[TT][CPG])
{
    constexpr int NJ = TT + 7;
    const int jlo = jhi0 - 7;
    const float* xsj = xs + (ptrdiff_t)jlo * JSTR;
    for (int ci = 0; ci < CIN; ++ci) {               // rolled (unroll regresses: r7/r8)
        float xv[NJ];
        if constexpr (GUARD) {
            const float* xpc = xs + (size_t)ci * cistride;
#pragma unroll
            for (int q = 0; q < NJ; ++q) {
                const int j = jlo + q;
                xv[q] = (j >= 0 && j < Lin) ? xpc[(ptrdiff_t)j * JSTR] : 0.f;
            }
        } else {
            const float* xpc = xsj + (size_t)ci * cistride;
#pragma unroll
            for (int q = 0; q < NJ; ++q)
                xv[q] = xpc[q * JSTR];               // imm-offset loads
        }
        const float* wc = wk + ci * wco;
#pragma unroll
        for (int d = 0; d < 8; ++d) {
            const float* wd = wc + d * CIN * wco;
            float wv[CPG];
            if constexpr ((CPG & 3) == 0) {
#pragma unroll
                for (int cq = 0; cq < CPG; cq += 4) {
                    const float4 w4 = *reinterpret_cast<const float4*>(wd + cq);
                    wv[cq + 0] = w4.x; wv[cq + 1] = w4.y;
                    wv[cq + 2] = w4.z; wv[cq + 3] = w4.w;
                }
            } else {
#pragma unroll
                for (int co = 0; co < CPG; ++co) wv[co] = wd[co];
            }
#pragma unroll
            for (int tt = 0; tt < TT; ++tt) {
                const float xx = xv[7 + tt - d];
#pragma unroll
                for (int co = 0; co < CPG; ++co)
                    acc[tt][co] = fmaf(xx, wv[co], acc[tt][co]);
            }
        }
    }
}

template<int CIN, int COUT, int TT, int COG, int MINW, int JSTR>
__global__ __launch_bounds__(256, MINW) void convt3_kernel(
    const float* __restrict__ x, size_t sfc_xstride, int cistride,
    const float* __restrict__ wp, int sfc_wstride,
    const float* __restrict__ bias, int sfc_bstride,
    float* __restrict__ y, size_t sfc_ystride,
    int Lin, int Lout)
{
    constexpr int CPG = COUT / COG;
    const int b = threadIdx.x & 63;
    const int widx = __builtin_amdgcn_readfirstlane(threadIdx.x >> 6);
    const int t0 = blockIdx.x * (4 * TT) + widx;
    if (t0 >= Lout) return;
    const int cb = blockIdx.z * CPG;
    const int k0   = (t0 + 16) & 3;
    const int jhi0 = (t0 + 16) >> 2;
    const float* xs = x + (size_t)blockIdx.y * sfc_xstride + b;
    const float* wk = wp + blockIdx.y * sfc_wstride + k0 * (8 * CIN * COUT) + cb;
    const float* bs = bias + blockIdx.y * sfc_bstride + cb;

    float acc[TT][CPG];
#pragma unroll
    for (int co = 0; co < CPG; ++co) {
        const float bv = bs[co];
#pragma unroll
        for (int tt = 0; tt < TT; ++tt) acc[tt][co] = bv;
    }

    const bool interior = (jhi0 >= 7) && (jhi0 + TT - 1 < Lin);
    if (interior)
        conv_core<CIN, CPG, TT, JSTR, false>(xs, cistride, Lin, wk, COUT, jhi0, acc);
    else
        conv_core<CIN, CPG, TT, JSTR, true >(xs, cistride, Lin, wk, COUT, jhi0, acc);

#pragma unroll
    for (int tt = 0; tt < TT; ++tt) {
        const int t = t0 + 4 * tt;
        if (t < Lout) {
#pragma unroll
            for (int co = 0; co < CPG; ++co)
                y[(size_t)blockIdx.y * sfc_ystride + ((size_t)(cb + co) * Lout + t) * 64 + b] =
                    ftanh(acc[tt][co]);
        }
    }
}

// ---------------- conv4 specialized: COUT=1, SGPR weights, imm offsets ----------
template<int CIN, int TT, bool GUARD>
__device__ __forceinline__ void conv4_core(
    const float* __restrict__ xs, int cistride, int Lin, int jhi0,
    const float (&wreg)[8][CIN], float (&acc)[TT])
{
    constexpr int NJ = TT + 7;
    const int jlo = jhi0 - 7;
    const float* xsj = xs + (ptrdiff_t)jlo * 64;
    for (int ci = 0; ci < CIN; ++ci) {       // rolled
        float xv[NJ];
        if constexpr (GUARD) {
            const float* xpc = xs + (size_t)ci * cistride;
#pragma unroll
            for (int q = 0; q < NJ; ++q) {
                const int j = jlo + q;
                xv[q] = (j >= 0 && j < Lin) ? xpc[(ptrdiff_t)j * 64] : 0.f;
            }
        } else {
            const float* xpc = xsj + (size_t)ci * cistride;
#pragma unroll
            for (int q = 0; q < NJ; ++q)
                xv[q] = xpc[q * 64];                 // imm-offset loads
        }
#pragma unroll
        for (int d = 0; d < 8; ++d)
#pragma unroll
            for (int tt = 0; tt < TT; ++tt)
                acc[tt] = fmaf(xv[7 + tt - d], wreg[d][ci], acc[tt]);
    }
}

template<int CIN, int TT, int MINW>
__global__ __launch_bounds__(256, MINW) void convt4_kernel(
    const float* __restrict__ x, size_t sfc_xstride, int cistride,
    const float* __restrict__ wp, int sfc_wstride,
    const float* __restrict__ bias, int sfc_bstride,
    float* __restrict__ y, size_t sfc_ystride, int Lin, int Lout)
{
    const int b = threadIdx.x & 63;
    const int widx = __builtin_amdgcn_readfirstlane(threadIdx.x >> 6);
    const int t0 = blockIdx.x * (4 * TT) + widx;
    if (t0 >= Lout) return;
    const int k0   = (t0 + 16) & 3;
    const int jhi0 = (t0 + 16) >> 2;
    const float* wk = wp + blockIdx.y * sfc_wstride + k0 * (8 * CIN);
    float wreg[8][CIN];
#pragma unroll
    for (int d = 0; d < 8; ++d)
#pragma unroll
        for (int ci = 0; ci < CIN; ++ci)
            wreg[d][ci] = wk[d * CIN + ci];
    const float bv = bias[blockIdx.y * sfc_bstride];
    float acc[TT];
#pragma unroll
    for (int tt = 0; tt < TT; ++tt) acc[tt] = bv;
    const float* xs = x + (size_t)blockIdx.y * sfc_xstride + b;

    const bool interior = (jhi0 >= 7) && (jhi0 + TT - 1 < Lin);
    if (interior) conv4_core<CIN, TT, false>(xs, cistride, Lin, jhi0, wreg, acc);
    else          conv4_core<CIN, TT, true >(xs, cistride, Lin, jhi0, wreg, acc);

    float* yb = y + (size_t)blockIdx.y * sfc_ystride;
#pragma unroll
    for (int tt = 0; tt < TT; ++tt) {
        const int t = t0 + 4 * tt;
        if (t < Lout) yb[(size_t)t * 64 + b] = ftanh(acc[tt]);
    }
}

// ---------------- Final gather + NearestNeighbouring (rolling window) ----------------
// minus[n]=inv[n-1], ord[n]=inv[n], plus[n]=inv[n+1] (clamped at ends): a wave's 4
// consecutive n need only the 6 rows at positions n0-1..n0+4 -> 12 gathers/wave total.
__global__ __launch_bounds__(256) void final_kernel(
    const float* __restrict__ d0, const float* __restrict__ d1,
    const float* __restrict__ nn_w, const float* __restrict__ nn_b,
    const int* __restrict__ oi,
    float* __restrict__ out)
{
    __shared__ float zl[16][65];
    const int tid = threadIdx.x;
    const int b = tid & 63;
    const int widx = __builtin_amdgcn_readfirstlane(tid >> 6);
    const int nblk = blockIdx.x * 16;
    const int n0 = nblk + widx * 4;

    float g[2][6];
#pragma unroll
    for (int s = 0; s < 2; ++s) {
        const float* dd = s ? d1 : d0;
        const int* ois = oi + s * NNODES;
#pragma unroll
        for (int q = 0; q < 6; ++q) {
            int pos = n0 - 1 + q;
            pos = pos < 0 ? 0 : (pos > NNODES - 1 ? NNODES - 1 : pos);
            g[s][q] = dd[(size_t)ois[pos] * 64 + b];
        }
    }
#pragma unroll
    for (int nn = 0; nn < 4; ++nn) {
        const int n = n0 + nn;
        float z = 0.f;
#pragma unroll
        for (int s = 0; s < 2; ++s) {
            const float* wv = nn_w + (size_t)(s * NNODES + n) * 3;
            z += ftanh(wv[0] * g[s][nn] + wv[1] * g[s][nn + 1]
                     + wv[2] * g[s][nn + 2] + nn_b[s * NNODES + n]);
        }
        zl[widx * 4 + nn][b] = ftanh(z);
    }
    __syncthreads();
    const int bq = tid >> 2;
    const int nq = tid & 3;
    float4 v;
    v.x = zl[nq * 4 + 0][bq];
    v.y = zl[nq * 4 + 1][bq];
    v.z = zl[nq * 4 + 2][bq];
    v.w = zl[nq * 4 + 3][bq];
    *reinterpret_cast<float4*>(out + (size_t)bq * NNODES + nblk + nq * 4) = v;
}

extern "C" void kernel_launch(void* const* d_in, const int* in_sizes, int n_in,
                              void* d_out, int out_size, void* d_ws, size_t ws_size,
                              hipStream_t stream)
{
    const float* x     = (const float*)d_in[0];
    const float* fc_w1 = (const float*)d_in[1];
    const float* fc_b1 = (const float*)d_in[2];
    const float* fc_w2 = (const float*)d_in[3];
    const float* fc_b2 = (const float*)d_in[4];
    const float* nn_w  = (const float*)d_in[5];
    const float* nn_b  = (const float*)d_in[6];
    const int* ord_i   = (const int*)d_in[7];
    const float* conv_w1 = (const float*)d_in[10];
    const float* conv_b1 = (const float*)d_in[11];
    const float* conv_w2 = (const float*)d_in[12];
    const float* conv_b2 = (const float*)d_in[13];
    const float* conv_w3 = (const float*)d_in[14];
    const float* conv_b3 = (const float*)d_in[15];
    const float* conv_w4 = (const float*)d_in[16];
    const float* conv_b4 = (const float*)d_in[17];
    float* out = (float*)d_out;

    const size_t SZ_Y1 = (size_t)16 * 1601 * 64;
    const size_t SZ_Y2 = (size_t)16 * 6401 * 64;
    const size_t SZ_Y3 = (size_t)8  * 25601 * 64;
    const size_t SZ_Y4 = (size_t)NNODES * 64;

    const size_t need22 = 56638976ull * 4;   // NS=2, NY3=2
    const size_t need21 = 43531264ull * 4;   // NS=2, NY3=1
    int NS = 1, NY3 = 1;
    if (ws_size >= need22)      { NS = 2; NY3 = 2; }
    else if (ws_size >= need21) { NS = 2; NY3 = 1; }

    float* ws  = (float*)d_ws;
    float* h1t = ws;
    float* h2t = h1t + 65536;
    float* y1  = h2t + 821248;
    float* y2  = y1  + (size_t)NS * SZ_Y1;
    float* y3  = y2  + (size_t)NS * SZ_Y2;
    float* y4  = y3  + (size_t)NY3 * SZ_Y3;
    float* wp1 = y4  + 2 * SZ_Y4;
    float* wp2 = wp1 + 16384;
    float* wp3 = wp2 + 16384;
    float* wp4 = wp3 + 8192;
    float* part = y3;   // fc2 partials alias y3 (consumed before convs)

    fc1_kernel<<<dim3(256),  dim3(256), 0, stream>>>(x, fc_w1, fc_b1, h1t);
    fc2_gemm_kernel<<<dim3(401, 4), dim3(128), 0, stream>>>(h1t, fc_w2, part);
    fc2_reduce_kernel<<<dim3(3208), dim3(256), 0, stream>>>(part, fc_b2, h2t);
    pack_all_kernel<<<dim3(162), dim3(256), 0, stream>>>(
        conv_w1, conv_w2, conv_w3, conv_w4, wp1, wp2, wp3, wp4);

    for (int s0 = 0; s0 < 2; s0 += NS) {
        // conv1: 16->16, 401 -> 1601; TT=1, co-split 2; JSTR=128
        convt3_kernel<16, 16, 1, 2, 8, 128><<<dim3(401, NS, 2), dim3(256), 0, stream>>>(
            h2t + s0 * 64, 64, 401 * 128,
            wp1 + s0 * 8192, 8192, conv_b1 + s0 * 16, 16,
            y1, SZ_Y1, 401, 1601);
        // conv2: 16->16, 1601 -> 6401; TT=4, co-split 2; MINW=6 (measured best)
        convt3_kernel<16, 16, 4, 2, 6, 64><<<dim3(401, NS, 2), dim3(256), 0, stream>>>(
            y1, SZ_Y1, 1601 * 64,
            wp2 + s0 * 8192, 8192, conv_b2 + s0 * 16, 16,
            y2, SZ_Y2, 1601, 6401);
        if (NY3 == 1) {
            for (int s = s0; s < s0 + NS; ++s) {
                const float* xin = y2 + (size_t)(NS == 2 ? (s - s0) : 0) * SZ_Y2;
                convt3_kernel<16, 8, 6, 1, 4, 64><<<dim3(1067, 1, 1), dim3(256), 0, stream>>>(
                    xin, 0, 6401 * 64,
                    wp3 + s * 4096, 0, conv_b3 + s * 8, 0,
                    y3, 0, 6401, 25601);
                convt4_kernel<8, 12, 8><<<dim3(2134, 1), dim3(256), 0, stream>>>(
                    y3, 0, 25601 * 64,
                    wp4 + s * 256, 0, conv_b4 + s, 0,
                    y4 + (size_t)s * SZ_Y4, 0, 25601, 102400);
            }
        }
    }
    if (NY3 == 2) {
        // conv3: 16->8, 6401 -> 25601; TT=6, CPG=8 (no co-split), MINW=4, both sfc
        // 2x arithmetic intensity vs TT6/CPG4 (384 FMA per 13-load window per ci)
        convt3_kernel<16, 8, 6, 1, 4, 64><<<dim3(1067, 2, 1), dim3(256), 0, stream>>>(
            y2, SZ_Y2, 6401 * 64,
            wp3, 4096, conv_b3, 8,
            y3, SZ_Y3, 6401, 25601);
        // conv4: 8->1, 25601 -> 102400; TT=12, MINW=8 (measured best)
        convt4_kernel<8, 12, 8><<<dim3(2134, 2), dim3(256), 0, stream>>>(
            y3, SZ_Y3, 25601 * 64,
            wp4, 256, conv_b4, 1,
            y4, SZ_Y4, 25601, 102400);
    }

    final_kernel<<<dim3(6400), dim3(256), 0, stream>>>(
        y4, y4 + SZ_Y4, nn_w, nn_b, ord_i, out);
}